// Round 1
// baseline (1807.525 us; speedup 1.0000x reference)
//
#include <hip/hip_runtime.h>
#include <cstdint>
#include <cstddef>

// ---------------------------------------------------------------------------
// TopoGNN: 3x SAGEConv(mean) + BN + ReLU, softmax-attention pooling, 2 heads.
// N=100000 nodes, E=1600000 edges, B=64 segments, IN_CH=6, HID=64.
// ---------------------------------------------------------------------------

// degree of dst (cnt in reference), reused by all 3 layers
__global__ __launch_bounds__(256) void deg_kernel(const int* __restrict__ dst,
                                                  float* __restrict__ deg, int E)
{
    int e = blockIdx.x * 256 + threadIdx.x;
    if (e < E) unsafeAtomicAdd(&deg[dst[e]], 1.0f);
}

// layer-1 aggregation: 6 channels, one thread per edge
__global__ __launch_bounds__(256) void agg6_kernel(const int* __restrict__ src,
                                                   const int* __restrict__ dst,
                                                   const float* __restrict__ x,
                                                   float* __restrict__ agg, int E)
{
    int e = blockIdx.x * 256 + threadIdx.x;
    if (e >= E) return;
    int s = src[e], d = dst[e];
#pragma unroll
    for (int c = 0; c < 6; c++)
        unsafeAtomicAdd(&agg[(size_t)d * 6 + c], x[(size_t)s * 6 + c]);
}

// 64-channel aggregation: one wave per edge, lane = channel
__global__ __launch_bounds__(256) void agg64_kernel(const int* __restrict__ src,
                                                    const int* __restrict__ dst,
                                                    const float* __restrict__ h,
                                                    float* __restrict__ agg, int E)
{
    int gid  = blockIdx.x * 256 + threadIdx.x;
    int w    = gid >> 6;        // edge id
    int lane = threadIdx.x & 63; // channel
    if (w >= E) return;
    int s = src[w], d = dst[w];
    unsafeAtomicAdd(&agg[(size_t)d * 64 + lane], h[(size_t)s * 64 + lane]);
}

// out[i][:] = (agg[i]/max(deg,1)) @ Wl + bias + hin[i] @ Wr   (K x 64 weights)
template <int K>
__global__ __launch_bounds__(256) void sage_matmul(
    const float* __restrict__ agg, const float* __restrict__ hin,
    const float* __restrict__ deg, const float* __restrict__ Wl,
    const float* __restrict__ bias, const float* __restrict__ Wr,
    float* __restrict__ out, int n)
{
    __shared__ float4 sWl[K * 16];
    __shared__ float4 sWr[K * 16];
    for (int i = threadIdx.x; i < K * 16; i += 256) {
        sWl[i] = ((const float4*)Wl)[i];
        sWr[i] = ((const float4*)Wr)[i];
    }
    __syncthreads();

    int node = blockIdx.x * 256 + threadIdx.x;
    if (node >= n) return;

    float invd = 1.0f / fmaxf(deg[node], 1.0f);
    float4 acc[16];
#pragma unroll
    for (int cg = 0; cg < 16; cg++) acc[cg] = ((const float4*)bias)[cg];

    const float* arow = agg + (size_t)node * K;
    const float* hrow = hin + (size_t)node * K;

    if constexpr (K % 4 == 0) {
#pragma unroll
        for (int k4 = 0; k4 < K / 4; k4++) {
            float4 av = ((const float4*)arow)[k4];
            float4 hv = ((const float4*)hrow)[k4];
            float aa[4] = {av.x, av.y, av.z, av.w};
            float hh[4] = {hv.x, hv.y, hv.z, hv.w};
#pragma unroll
            for (int j = 0; j < 4; j++) {
                float am = aa[j] * invd;
                float hk = hh[j];
                int   k  = k4 * 4 + j;
#pragma unroll
                for (int cg = 0; cg < 16; cg++) {
                    float4 wl = sWl[k * 16 + cg];
                    float4 wr = sWr[k * 16 + cg];
                    acc[cg].x = fmaf(am, wl.x, fmaf(hk, wr.x, acc[cg].x));
                    acc[cg].y = fmaf(am, wl.y, fmaf(hk, wr.y, acc[cg].y));
                    acc[cg].z = fmaf(am, wl.z, fmaf(hk, wr.z, acc[cg].z));
                    acc[cg].w = fmaf(am, wl.w, fmaf(hk, wr.w, acc[cg].w));
                }
            }
        }
    } else {
#pragma unroll
        for (int k = 0; k < K; k++) {
            float am = arow[k] * invd;
            float hk = hrow[k];
#pragma unroll
            for (int cg = 0; cg < 16; cg++) {
                float4 wl = sWl[k * 16 + cg];
                float4 wr = sWr[k * 16 + cg];
                acc[cg].x = fmaf(am, wl.x, fmaf(hk, wr.x, acc[cg].x));
                acc[cg].y = fmaf(am, wl.y, fmaf(hk, wr.y, acc[cg].y));
                acc[cg].z = fmaf(am, wl.z, fmaf(hk, wr.z, acc[cg].z));
                acc[cg].w = fmaf(am, wl.w, fmaf(hk, wr.w, acc[cg].w));
            }
        }
    }

    float4* orow = (float4*)(out + (size_t)node * 64);
#pragma unroll
    for (int cg = 0; cg < 16; cg++) orow[cg] = acc[cg];
}

// per-channel sum and sum-of-squares over all N rows (64 channels)
__global__ __launch_bounds__(256) void bn_stats(const float* __restrict__ h,
                                                float* __restrict__ stats, size_t total)
{
    __shared__ float ls[64], lss[64];
    if (threadIdx.x < 64) { ls[threadIdx.x] = 0.f; lss[threadIdx.x] = 0.f; }
    __syncthreads();
    float s = 0.f, ss = 0.f;
    size_t stride = (size_t)gridDim.x * 256;  // multiple of 64 -> channel fixed per thread
    for (size_t i = (size_t)blockIdx.x * 256 + threadIdx.x; i < total; i += stride) {
        float v = h[i];
        s += v;
        ss = fmaf(v, v, ss);
    }
    int c = threadIdx.x & 63;
    atomicAdd(&ls[c], s);
    atomicAdd(&lss[c], ss);
    __syncthreads();
    if (threadIdx.x < 64) {
        unsafeAtomicAdd(&stats[threadIdx.x], ls[threadIdx.x]);
        unsafeAtomicAdd(&stats[64 + threadIdx.x], lss[threadIdx.x]);
    }
}

// h = relu((h - mu) * rsqrt(var+eps) * g + be), in place
__global__ __launch_bounds__(256) void bn_relu(float* __restrict__ h,
                                               const float* __restrict__ stats,
                                               const float* __restrict__ g,
                                               const float* __restrict__ be,
                                               float inv_n, size_t total)
{
    size_t i = (size_t)blockIdx.x * 256 + threadIdx.x;
    if (i >= total) return;
    int   c   = threadIdx.x & 63;
    float mu  = stats[c] * inv_n;
    float var = stats[64 + c] * inv_n - mu * mu;
    float sc  = g[c] / sqrtf(var + 1e-5f);
    float sh  = fmaf(-mu, sc, be[c]);
    h[i] = fmaxf(fmaf(h[i], sc, sh), 0.f);
}

// sum over nodes of exp(x[i,4])  (softmax is shift-invariant: min-sub + 1e-8 drop out)
__global__ __launch_bounds__(256) void softmax_sum(const float* __restrict__ x,
                                                   float* __restrict__ sumexp, int n)
{
    float s = 0.f;
    int stride = gridDim.x * 256;
    for (int i = blockIdx.x * 256 + threadIdx.x; i < n; i += stride)
        s += expf(x[(size_t)i * 6 + 4]);
#pragma unroll
    for (int o = 32; o > 0; o >>= 1) s += __shfl_down(s, o, 64);
    __shared__ float wsum[4];
    if ((threadIdx.x & 63) == 0) wsum[threadIdx.x >> 6] = s;
    __syncthreads();
    if (threadIdx.x == 0)
        unsafeAtomicAdd(sumexp, wsum[0] + wsum[1] + wsum[2] + wsum[3]);
}

// lower_bound of each segment id in the sorted batch array (65 entries, lb[64]=N)
__global__ void seg_bounds(const int* __restrict__ batch, int* __restrict__ lb, int n)
{
    int b = threadIdx.x;
    if (b > 64) return;
    int lo = 0, hi = n;
    while (lo < hi) {
        int mid = (lo + hi) >> 1;
        if (batch[mid] < b) lo = mid + 1; else hi = mid;
    }
    lb[b] = lo;
}

// pool[b][c] = sum_{i in seg b} h[i][c] * exp(pw_i)/sumexp / max(cnt_b,1)
__global__ __launch_bounds__(256) void pool_kernel(const float* __restrict__ h,
                                                   const float* __restrict__ x,
                                                   const int* __restrict__ lb,
                                                   const float* __restrict__ sumexp,
                                                   float* __restrict__ pool, int n)
{
    int b = blockIdx.x;
    int start = lb[b], end = lb[b + 1];
    int c = threadIdx.x & 63, grp = threadIdx.x >> 6;
    float inv_se = 1.0f / sumexp[0];
    float acc = 0.f;
    for (int i = start + grp; i < end; i += 4) {
        float w = expf(x[(size_t)i * 6 + 4]) * inv_se;
        acc = fmaf(h[(size_t)i * 64 + c], w, acc);
    }
    __shared__ float red[4][64];
    red[grp][c] = acc;
    __syncthreads();
    if (grp == 0) {
        float cnt = (float)(end - start);
        pool[b * 64 + c] = (red[0][c] + red[1][c] + red[2][c] + red[3][c]) / fmaxf(cnt, 1.0f);
    }
}

// tiny MLP heads: phase logits (64x3) then sigmoid transition (64x1)
__global__ __launch_bounds__(64) void heads_kernel(
    const float* __restrict__ pool,
    const float* __restrict__ phW1, const float* __restrict__ phb1,
    const float* __restrict__ phW2, const float* __restrict__ phb2,
    const float* __restrict__ trW1, const float* __restrict__ trb1,
    const float* __restrict__ trW2, const float* __restrict__ trb2,
    float* __restrict__ out)
{
    int b = blockIdx.x, t = threadIdx.x;
    __shared__ float p[64], h1[32], h2[16];
    p[t] = pool[b * 64 + t];
    __syncthreads();
    if (t < 32) {
        float s = phb1[t];
        for (int k = 0; k < 64; k++) s = fmaf(p[k], phW1[k * 32 + t], s);
        h1[t] = fmaxf(s, 0.f);
    } else if (t < 48) {
        int tt = t - 32;
        float s = trb1[tt];
        for (int k = 0; k < 64; k++) s = fmaf(p[k], trW1[k * 16 + tt], s);
        h2[tt] = fmaxf(s, 0.f);
    }
    __syncthreads();
    if (t < 3) {
        float s = phb2[t];
        for (int k = 0; k < 32; k++) s = fmaf(h1[k], phW2[k * 3 + t], s);
        out[b * 3 + t] = s;
    } else if (t == 63) {
        float s = trb2[0];
        for (int k = 0; k < 16; k++) s = fmaf(h2[k], trW2[k], s);
        out[192 + b] = 1.0f / (1.0f + expf(-s));
    }
}

extern "C" void kernel_launch(void* const* d_in, const int* in_sizes, int n_in,
                              void* d_out, int out_size, void* d_ws, size_t ws_size,
                              hipStream_t stream)
{
    const float* x     = (const float*)d_in[0];
    const int*   ei    = (const int*)d_in[1];
    const int*   batch = (const int*)d_in[2];
    const float* W1l = (const float*)d_in[3];
    const float* b1  = (const float*)d_in[4];
    const float* W1r = (const float*)d_in[5];
    const float* W2l = (const float*)d_in[6];
    const float* b2  = (const float*)d_in[7];
    const float* W2r = (const float*)d_in[8];
    const float* W3l = (const float*)d_in[9];
    const float* b3  = (const float*)d_in[10];
    const float* W3r = (const float*)d_in[11];
    const float* g1  = (const float*)d_in[12];
    const float* be1 = (const float*)d_in[13];
    const float* g2  = (const float*)d_in[14];
    const float* be2 = (const float*)d_in[15];
    const float* g3  = (const float*)d_in[16];
    const float* be3 = (const float*)d_in[17];
    const float* phW1 = (const float*)d_in[18];
    const float* phb1 = (const float*)d_in[19];
    const float* phW2 = (const float*)d_in[20];
    const float* phb2 = (const float*)d_in[21];
    const float* trW1 = (const float*)d_in[22];
    const float* trb1 = (const float*)d_in[23];
    const float* trW2 = (const float*)d_in[24];
    const float* trb2 = (const float*)d_in[25];

    const int N = in_sizes[0] / 6;
    const int E = in_sizes[1] / 2;
    const int* src = ei;
    const int* dst = ei + E;

    float* ws = (float*)d_ws;
    const size_t N64 = (size_t)N * 64;
    float* agg    = ws;                 // N*64
    float* hA     = ws + N64;           // N*64
    float* hB     = ws + 2 * N64;       // N*64
    float* deg    = ws + 3 * N64;       // N (padded to /4)
    float* stats  = deg + (((size_t)N + 3) & ~(size_t)3);  // 128
    float* sumexp = stats + 128;        // 1 (pad 4)
    int*   lb     = (int*)(sumexp + 4); // 65 (pad 72)
    float* pool   = sumexp + 4 + 72;    // 64*64
    float* out    = (float*)d_out;

    const int nodeBlocks = (N + 255) / 256;
    const int edgeBlocks = (E + 255) / 256;
    const int waveEdgeBlocks = (int)(((size_t)E * 64 + 255) / 256);
    const int ewBlocks = (int)((N64 + 255) / 256);
    const float invN = 1.0f / (float)N;

    // degree (shared by all 3 layers)
    hipMemsetAsync(deg, 0, (size_t)N * sizeof(float), stream);
    deg_kernel<<<edgeBlocks, 256, 0, stream>>>(dst, deg, E);

    // ---- layer 1 ----
    hipMemsetAsync(agg, 0, (size_t)N * 6 * sizeof(float), stream);
    agg6_kernel<<<edgeBlocks, 256, 0, stream>>>(src, dst, x, agg, E);
    sage_matmul<6><<<nodeBlocks, 256, 0, stream>>>(agg, x, deg, W1l, b1, W1r, hA, N);
    hipMemsetAsync(stats, 0, 128 * sizeof(float), stream);
    bn_stats<<<1024, 256, 0, stream>>>(hA, stats, N64);
    bn_relu<<<ewBlocks, 256, 0, stream>>>(hA, stats, g1, be1, invN, N64);

    // ---- layer 2 ----
    hipMemsetAsync(agg, 0, N64 * sizeof(float), stream);
    agg64_kernel<<<waveEdgeBlocks, 256, 0, stream>>>(src, dst, hA, agg, E);
    sage_matmul<64><<<nodeBlocks, 256, 0, stream>>>(agg, hA, deg, W2l, b2, W2r, hB, N);
    hipMemsetAsync(stats, 0, 128 * sizeof(float), stream);
    bn_stats<<<1024, 256, 0, stream>>>(hB, stats, N64);
    bn_relu<<<ewBlocks, 256, 0, stream>>>(hB, stats, g2, be2, invN, N64);

    // ---- layer 3 ----
    hipMemsetAsync(agg, 0, N64 * sizeof(float), stream);
    agg64_kernel<<<waveEdgeBlocks, 256, 0, stream>>>(src, dst, hB, agg, E);
    sage_matmul<64><<<nodeBlocks, 256, 0, stream>>>(agg, hB, deg, W3l, b3, W3r, hA, N);
    hipMemsetAsync(stats, 0, 128 * sizeof(float), stream);
    bn_stats<<<1024, 256, 0, stream>>>(hA, stats, N64);
    bn_relu<<<ewBlocks, 256, 0, stream>>>(hA, stats, g3, be3, invN, N64);

    // ---- attention pooling + heads ----
    hipMemsetAsync(sumexp, 0, sizeof(float), stream);
    softmax_sum<<<256, 256, 0, stream>>>(x, sumexp, N);
    seg_bounds<<<1, 128, 0, stream>>>(batch, lb, N);
    pool_kernel<<<64, 256, 0, stream>>>(hA, x, lb, sumexp, pool, N);
    heads_kernel<<<64, 64, 0, stream>>>(pool, phW1, phb1, phW2, phb2,
                                        trW1, trb1, trW2, trb2, out);
}

// Round 2
// 1123.826 us; speedup vs baseline: 1.6084x; 1.6084x over previous
//
#include <hip/hip_runtime.h>
#include <cstdint>
#include <cstddef>

// ---------------------------------------------------------------------------
// TopoGNN: 3x SAGEConv(mean) + BN + ReLU, softmax-attention pooling, 2 heads.
// N=100000 nodes, E=1600000 edges, B=64 segments, IN_CH=6, HID=64.
// R1: scatter-atomic aggregation (213M float atomics, ~1.3ms) replaced with
// per-call CSR build (1.6M int atomics) + pull-mode register aggregation.
// ---------------------------------------------------------------------------

// ---- CSR build ------------------------------------------------------------

__global__ __launch_bounds__(256) void hist_kernel(const int* __restrict__ dst,
                                                   int* __restrict__ degi, int E)
{
    int e = blockIdx.x * 256 + threadIdx.x;
    if (e < E) atomicAdd(&degi[dst[e]], 1);
}

// single-block exclusive scan: degi[N] -> rowptr[N+1]
__global__ __launch_bounds__(1024) void scan_kernel(const int* __restrict__ degi,
                                                    int* __restrict__ rowptr, int N)
{
    __shared__ int s[1024];
    int t = threadIdx.x;
    int chunk = (N + 1023) / 1024;
    int begin = t * chunk;
    int end   = min(begin + chunk, N);
    int sum = 0;
    for (int i = begin; i < end; i++) sum += degi[i];
    s[t] = sum;
    __syncthreads();
    // Hillis-Steele inclusive scan over the 1024 block sums
    for (int off = 1; off < 1024; off <<= 1) {
        int v = (t >= off) ? s[t - off] : 0;
        __syncthreads();
        s[t] += v;
        __syncthreads();
    }
    int run = (t == 0) ? 0 : s[t - 1];
    for (int i = begin; i < end; i++) { rowptr[i] = run; run += degi[i]; }
    if (t == 1023) rowptr[N] = run;   // == E (last chunks may be empty; run = total)
}

// cursor starts as a copy of rowptr[0..N-1]; eidx[pos] = src for edges grouped by dst
__global__ __launch_bounds__(256) void scatter_kernel(const int* __restrict__ src,
                                                      const int* __restrict__ dst,
                                                      int* __restrict__ cursor,
                                                      int* __restrict__ eidx, int E)
{
    int e = blockIdx.x * 256 + threadIdx.x;
    if (e >= E) return;
    int pos = atomicAdd(&cursor[dst[e]], 1);
    eidx[pos] = src[e];
}

// ---- layer 1: fused pull-aggregation (6 ch) + matmul ----------------------
// out[i][:] = (sum_nbr x[s]/max(deg,1)) @ Wl + b + x[i] @ Wr
__global__ __launch_bounds__(256) void sage1_fused(
    const int* __restrict__ rowptr, const int* __restrict__ eidx,
    const float* __restrict__ x,
    const float* __restrict__ Wl, const float* __restrict__ bias,
    const float* __restrict__ Wr, float* __restrict__ out, int n)
{
    __shared__ float4 sWl[6 * 16];
    __shared__ float4 sWr[6 * 16];
    for (int i = threadIdx.x; i < 6 * 16; i += 256) {
        sWl[i] = ((const float4*)Wl)[i];
        sWr[i] = ((const float4*)Wr)[i];
    }
    __syncthreads();

    int node = blockIdx.x * 256 + threadIdx.x;
    if (node >= n) return;

    int b = rowptr[node], e = rowptr[node + 1];
    float a[6] = {0.f, 0.f, 0.f, 0.f, 0.f, 0.f};
    for (int j = b; j < e; j++) {
        int s = eidx[j];
        const float2* r = (const float2*)(x + (size_t)s * 6);  // s*6 even -> 8B aligned
        float2 r0 = r[0], r1 = r[1], r2 = r[2];
        a[0] += r0.x; a[1] += r0.y; a[2] += r1.x;
        a[3] += r1.y; a[4] += r2.x; a[5] += r2.y;
    }
    float invd = 1.0f / fmaxf((float)(e - b), 1.0f);

    const float2* xr2 = (const float2*)(x + (size_t)node * 6);
    float2 x0 = xr2[0], x1 = xr2[1], x2 = xr2[2];
    float hh[6] = {x0.x, x0.y, x1.x, x1.y, x2.x, x2.y};

    float4 acc[16];
#pragma unroll
    for (int cg = 0; cg < 16; cg++) acc[cg] = ((const float4*)bias)[cg];
#pragma unroll
    for (int k = 0; k < 6; k++) {
        float am = a[k] * invd;
        float hk = hh[k];
#pragma unroll
        for (int cg = 0; cg < 16; cg++) {
            float4 wl = sWl[k * 16 + cg];
            float4 wr = sWr[k * 16 + cg];
            acc[cg].x = fmaf(am, wl.x, fmaf(hk, wr.x, acc[cg].x));
            acc[cg].y = fmaf(am, wl.y, fmaf(hk, wr.y, acc[cg].y));
            acc[cg].z = fmaf(am, wl.z, fmaf(hk, wr.z, acc[cg].z));
            acc[cg].w = fmaf(am, wl.w, fmaf(hk, wr.w, acc[cg].w));
        }
    }
    float4* orow = (float4*)(out + (size_t)node * 64);
#pragma unroll
    for (int cg = 0; cg < 16; cg++) orow[cg] = acc[cg];
}

// ---- 64-ch pull aggregation: one wave per node, lane = channel ------------
__global__ __launch_bounds__(256) void aggpull64(const int* __restrict__ rowptr,
                                                 const int* __restrict__ eidx,
                                                 const float* __restrict__ h,
                                                 float* __restrict__ agg, int n)
{
    int w    = (blockIdx.x * 256 + threadIdx.x) >> 6;
    int lane = threadIdx.x & 63;
    if (w >= n) return;
    int b = rowptr[w], e = rowptr[w + 1];
    float acc = 0.f;
    for (int j0 = b; j0 < e; j0 += 64) {
        // coalesced vector load of up to 64 neighbor ids, then broadcast via shfl
        int myidx = (j0 + lane < e) ? eidx[j0 + lane] : 0;
        int m = min(64, e - j0);
        for (int jj = 0; jj < m; jj++) {
            int s = __shfl(myidx, jj, 64);
            acc += h[(size_t)s * 64 + lane];
        }
    }
    agg[(size_t)w * 64 + lane] = acc;
}

// out[i][:] = (agg[i]/max(deg,1)) @ Wl + bias + hin[i] @ Wr   (64x64 weights)
__global__ __launch_bounds__(256) void sage_matmul64(
    const float* __restrict__ agg, const float* __restrict__ hin,
    const int* __restrict__ rowptr, const float* __restrict__ Wl,
    const float* __restrict__ bias, const float* __restrict__ Wr,
    float* __restrict__ out, int n)
{
    __shared__ float4 sWl[64 * 16];
    __shared__ float4 sWr[64 * 16];
    for (int i = threadIdx.x; i < 64 * 16; i += 256) {
        sWl[i] = ((const float4*)Wl)[i];
        sWr[i] = ((const float4*)Wr)[i];
    }
    __syncthreads();

    int node = blockIdx.x * 256 + threadIdx.x;
    if (node >= n) return;

    float invd = 1.0f / fmaxf((float)(rowptr[node + 1] - rowptr[node]), 1.0f);
    float4 acc[16];
#pragma unroll
    for (int cg = 0; cg < 16; cg++) acc[cg] = ((const float4*)bias)[cg];

    const float* arow = agg + (size_t)node * 64;
    const float* hrow = hin + (size_t)node * 64;

#pragma unroll
    for (int k4 = 0; k4 < 16; k4++) {
        float4 av = ((const float4*)arow)[k4];
        float4 hv = ((const float4*)hrow)[k4];
        float aa[4] = {av.x, av.y, av.z, av.w};
        float hh[4] = {hv.x, hv.y, hv.z, hv.w};
#pragma unroll
        for (int j = 0; j < 4; j++) {
            float am = aa[j] * invd;
            float hk = hh[j];
            int   k  = k4 * 4 + j;
#pragma unroll
            for (int cg = 0; cg < 16; cg++) {
                float4 wl = sWl[k * 16 + cg];
                float4 wr = sWr[k * 16 + cg];
                acc[cg].x = fmaf(am, wl.x, fmaf(hk, wr.x, acc[cg].x));
                acc[cg].y = fmaf(am, wl.y, fmaf(hk, wr.y, acc[cg].y));
                acc[cg].z = fmaf(am, wl.z, fmaf(hk, wr.z, acc[cg].z));
                acc[cg].w = fmaf(am, wl.w, fmaf(hk, wr.w, acc[cg].w));
            }
        }
    }
    float4* orow = (float4*)(out + (size_t)node * 64);
#pragma unroll
    for (int cg = 0; cg < 16; cg++) orow[cg] = acc[cg];
}

// ---- BatchNorm ------------------------------------------------------------

__global__ __launch_bounds__(256) void bn_stats(const float* __restrict__ h,
                                                float* __restrict__ stats, size_t total)
{
    __shared__ float ls[64], lss[64];
    if (threadIdx.x < 64) { ls[threadIdx.x] = 0.f; lss[threadIdx.x] = 0.f; }
    __syncthreads();
    float s = 0.f, ss = 0.f;
    size_t stride = (size_t)gridDim.x * 256;  // multiple of 64 -> channel fixed per thread
    for (size_t i = (size_t)blockIdx.x * 256 + threadIdx.x; i < total; i += stride) {
        float v = h[i];
        s += v;
        ss = fmaf(v, v, ss);
    }
    int c = threadIdx.x & 63;
    atomicAdd(&ls[c], s);
    atomicAdd(&lss[c], ss);
    __syncthreads();
    if (threadIdx.x < 64) {
        unsafeAtomicAdd(&stats[threadIdx.x], ls[threadIdx.x]);
        unsafeAtomicAdd(&stats[64 + threadIdx.x], lss[threadIdx.x]);
    }
}

__global__ __launch_bounds__(256) void bn_relu(float* __restrict__ h,
                                               const float* __restrict__ stats,
                                               const float* __restrict__ g,
                                               const float* __restrict__ be,
                                               float inv_n, size_t total)
{
    size_t i = (size_t)blockIdx.x * 256 + threadIdx.x;
    if (i >= total) return;
    int   c   = threadIdx.x & 63;
    float mu  = stats[c] * inv_n;
    float var = stats[64 + c] * inv_n - mu * mu;
    float sc  = g[c] / sqrtf(var + 1e-5f);
    float sh  = fmaf(-mu, sc, be[c]);
    h[i] = fmaxf(fmaf(h[i], sc, sh), 0.f);
}

// ---- pooling + heads ------------------------------------------------------

// sum over nodes of exp(x[i,4])  (softmax is shift-invariant: min-sub + 1e-8 drop out)
__global__ __launch_bounds__(256) void softmax_sum(const float* __restrict__ x,
                                                   float* __restrict__ sumexp, int n)
{
    float s = 0.f;
    int stride = gridDim.x * 256;
    for (int i = blockIdx.x * 256 + threadIdx.x; i < n; i += stride)
        s += expf(x[(size_t)i * 6 + 4]);
#pragma unroll
    for (int o = 32; o > 0; o >>= 1) s += __shfl_down(s, o, 64);
    __shared__ float wsum[4];
    if ((threadIdx.x & 63) == 0) wsum[threadIdx.x >> 6] = s;
    __syncthreads();
    if (threadIdx.x == 0)
        unsafeAtomicAdd(sumexp, wsum[0] + wsum[1] + wsum[2] + wsum[3]);
}

// lower_bound of each segment id in the sorted batch array (65 entries, lb[64]=N)
__global__ void seg_bounds(const int* __restrict__ batch, int* __restrict__ lb, int n)
{
    int b = threadIdx.x;
    if (b > 64) return;
    int lo = 0, hi = n;
    while (lo < hi) {
        int mid = (lo + hi) >> 1;
        if (batch[mid] < b) lo = mid + 1; else hi = mid;
    }
    lb[b] = lo;
}

// pool[b][c] = sum_{i in seg b} h[i][c] * exp(pw_i)/sumexp / max(cnt_b,1)
__global__ __launch_bounds__(256) void pool_kernel(const float* __restrict__ h,
                                                   const float* __restrict__ x,
                                                   const int* __restrict__ lb,
                                                   const float* __restrict__ sumexp,
                                                   float* __restrict__ pool, int n)
{
    int b = blockIdx.x;
    int start = lb[b], end = lb[b + 1];
    int c = threadIdx.x & 63, grp = threadIdx.x >> 6;
    float inv_se = 1.0f / sumexp[0];
    float acc = 0.f;
    for (int i = start + grp; i < end; i += 4) {
        float w = expf(x[(size_t)i * 6 + 4]) * inv_se;
        acc = fmaf(h[(size_t)i * 64 + c], w, acc);
    }
    __shared__ float red[4][64];
    red[grp][c] = acc;
    __syncthreads();
    if (grp == 0) {
        float cnt = (float)(end - start);
        pool[b * 64 + c] = (red[0][c] + red[1][c] + red[2][c] + red[3][c]) / fmaxf(cnt, 1.0f);
    }
}

__global__ __launch_bounds__(64) void heads_kernel(
    const float* __restrict__ pool,
    const float* __restrict__ phW1, const float* __restrict__ phb1,
    const float* __restrict__ phW2, const float* __restrict__ phb2,
    const float* __restrict__ trW1, const float* __restrict__ trb1,
    const float* __restrict__ trW2, const float* __restrict__ trb2,
    float* __restrict__ out)
{
    int b = blockIdx.x, t = threadIdx.x;
    __shared__ float p[64], h1[32], h2[16];
    p[t] = pool[b * 64 + t];
    __syncthreads();
    if (t < 32) {
        float s = phb1[t];
        for (int k = 0; k < 64; k++) s = fmaf(p[k], phW1[k * 32 + t], s);
        h1[t] = fmaxf(s, 0.f);
    } else if (t < 48) {
        int tt = t - 32;
        float s = trb1[tt];
        for (int k = 0; k < 64; k++) s = fmaf(p[k], trW1[k * 16 + tt], s);
        h2[tt] = fmaxf(s, 0.f);
    }
    __syncthreads();
    if (t < 3) {
        float s = phb2[t];
        for (int k = 0; k < 32; k++) s = fmaf(h1[k], phW2[k * 3 + t], s);
        out[b * 3 + t] = s;
    } else if (t == 63) {
        float s = trb2[0];
        for (int k = 0; k < 16; k++) s = fmaf(h2[k], trW2[k], s);
        out[192 + b] = 1.0f / (1.0f + expf(-s));
    }
}

extern "C" void kernel_launch(void* const* d_in, const int* in_sizes, int n_in,
                              void* d_out, int out_size, void* d_ws, size_t ws_size,
                              hipStream_t stream)
{
    const float* x     = (const float*)d_in[0];
    const int*   ei    = (const int*)d_in[1];
    const int*   batch = (const int*)d_in[2];
    const float* W1l = (const float*)d_in[3];
    const float* b1  = (const float*)d_in[4];
    const float* W1r = (const float*)d_in[5];
    const float* W2l = (const float*)d_in[6];
    const float* b2  = (const float*)d_in[7];
    const float* W2r = (const float*)d_in[8];
    const float* W3l = (const float*)d_in[9];
    const float* b3  = (const float*)d_in[10];
    const float* W3r = (const float*)d_in[11];
    const float* g1  = (const float*)d_in[12];
    const float* be1 = (const float*)d_in[13];
    const float* g2  = (const float*)d_in[14];
    const float* be2 = (const float*)d_in[15];
    const float* g3  = (const float*)d_in[16];
    const float* be3 = (const float*)d_in[17];
    const float* phW1 = (const float*)d_in[18];
    const float* phb1 = (const float*)d_in[19];
    const float* phW2 = (const float*)d_in[20];
    const float* phb2 = (const float*)d_in[21];
    const float* trW1 = (const float*)d_in[22];
    const float* trb1 = (const float*)d_in[23];
    const float* trW2 = (const float*)d_in[24];
    const float* trb2 = (const float*)d_in[25];

    const int N = in_sizes[0] / 6;
    const int E = in_sizes[1] / 2;
    const int* src = ei;
    const int* dst = ei + E;

    float* ws = (float*)d_ws;
    const size_t N64 = (size_t)N * 64;
    float* agg    = ws;                  // N*64
    float* hA     = ws + N64;            // N*64
    float* hB     = ws + 2 * N64;        // N*64
    int*   degi   = (int*)(ws + 3 * N64);   // N  (doubles as scatter cursor)
    int*   rowptr = degi + N;               // N+1
    int*   eidx   = rowptr + N + 1;         // E
    float* stats  = (float*)(eidx + E);     // 128
    float* sumexp = stats + 128;            // 1 (pad 4)
    int*   lb     = (int*)(sumexp + 4);     // 65 (pad 72)
    float* pool   = (float*)(lb + 72);      // 64*64
    float* out    = (float*)d_out;

    const int nodeBlocks = (N + 255) / 256;
    const int edgeBlocks = (E + 255) / 256;
    const int waveNodeBlocks = (int)(((size_t)N * 64 + 255) / 256);
    const int ewBlocks = (int)((N64 + 255) / 256);
    const float invN = 1.0f / (float)N;

    // ---- CSR build (edges grouped by dst; eidx stores src) ----
    hipMemsetAsync(degi, 0, (size_t)N * sizeof(int), stream);
    hist_kernel<<<edgeBlocks, 256, 0, stream>>>(dst, degi, E);
    scan_kernel<<<1, 1024, 0, stream>>>(degi, rowptr, N);
    hipMemcpyAsync(degi, rowptr, (size_t)N * sizeof(int),
                   hipMemcpyDeviceToDevice, stream);           // degi now = cursor
    scatter_kernel<<<edgeBlocks, 256, 0, stream>>>(src, dst, degi, eidx, E);

    // ---- layer 1 (6 ch, aggregation fused into matmul) ----
    sage1_fused<<<nodeBlocks, 256, 0, stream>>>(rowptr, eidx, x, W1l, b1, W1r, hA, N);
    hipMemsetAsync(stats, 0, 128 * sizeof(float), stream);
    bn_stats<<<1024, 256, 0, stream>>>(hA, stats, N64);
    bn_relu<<<ewBlocks, 256, 0, stream>>>(hA, stats, g1, be1, invN, N64);

    // ---- layer 2 ----
    aggpull64<<<waveNodeBlocks, 256, 0, stream>>>(rowptr, eidx, hA, agg, N);
    sage_matmul64<<<nodeBlocks, 256, 0, stream>>>(agg, hA, rowptr, W2l, b2, W2r, hB, N);
    hipMemsetAsync(stats, 0, 128 * sizeof(float), stream);
    bn_stats<<<1024, 256, 0, stream>>>(hB, stats, N64);
    bn_relu<<<ewBlocks, 256, 0, stream>>>(hB, stats, g2, be2, invN, N64);

    // ---- layer 3 ----
    aggpull64<<<waveNodeBlocks, 256, 0, stream>>>(rowptr, eidx, hB, agg, N);
    sage_matmul64<<<nodeBlocks, 256, 0, stream>>>(agg, hB, rowptr, W3l, b3, W3r, hA, N);
    hipMemsetAsync(stats, 0, 128 * sizeof(float), stream);
    bn_stats<<<1024, 256, 0, stream>>>(hA, stats, N64);
    bn_relu<<<ewBlocks, 256, 0, stream>>>(hA, stats, g3, be3, invN, N64);

    // ---- attention pooling + heads ----
    hipMemsetAsync(sumexp, 0, sizeof(float), stream);
    softmax_sum<<<256, 256, 0, stream>>>(x, sumexp, N);
    seg_bounds<<<1, 128, 0, stream>>>(batch, lb, N);
    pool_kernel<<<64, 256, 0, stream>>>(hA, x, lb, sumexp, pool, N);
    heads_kernel<<<64, 64, 0, stream>>>(pool, phW1, phb1, phW2, phb2,
                                        trW1, trb1, trW2, trb2, out);
}

// Round 3
// 857.683 us; speedup vs baseline: 2.1075x; 1.3103x over previous
//
#include <hip/hip_runtime.h>
#include <cstdint>
#include <cstddef>

// ---------------------------------------------------------------------------
// TopoGNN: 3x SAGEConv(mean) + BN + ReLU, softmax-attention pooling, 2 heads.
// N=100000 nodes, E=1600000 edges, B=64 segments, IN_CH=6, HID=64.
// R1: scatter atomics -> CSR build + pull-mode aggregation.
// R2: single-block scan (163us on 1 CU) -> 3-phase multi-block scan; fused
//     memsets; matmul 2 nodes/thread (LDS-broadcast-bound -> VALU-bound,
//     un-unrolled K loop for I-cache); aggpull 4-deep load pipelining.
// ---------------------------------------------------------------------------

// ---- CSR build ------------------------------------------------------------

__global__ __launch_bounds__(256) void hist_kernel(const int* __restrict__ dst,
                                                   int* __restrict__ degi, int E)
{
    int e = blockIdx.x * 256 + threadIdx.x;
    if (e < E) atomicAdd(&degi[dst[e]], 1);
}

// phase 1: per-block (512-element chunk) sums, coalesced int2 loads. N even.
__global__ __launch_bounds__(256) void scan_part1(const int* __restrict__ degi,
                                                  int* __restrict__ bsum, int N)
{
    int t  = threadIdx.x;
    int g2 = blockIdx.x * 256 + t;
    int n2 = N >> 1;
    int2 d = (g2 < n2) ? ((const int2*)degi)[g2] : make_int2(0, 0);
    int v = d.x + d.y;
#pragma unroll
    for (int o = 32; o > 0; o >>= 1) v += __shfl_down(v, o, 64);
    __shared__ int wsum[4];
    if ((t & 63) == 0) wsum[t >> 6] = v;
    __syncthreads();
    if (t == 0) bsum[blockIdx.x] = wsum[0] + wsum[1] + wsum[2] + wsum[3];
}

// phase 2: one block scans the <=256 chunk sums; writes rowptr[N]=E too.
__global__ __launch_bounds__(256) void scan_part2(const int* __restrict__ bsum,
                                                  int* __restrict__ boff,
                                                  int* __restrict__ rowptrN, int nb)
{
    __shared__ int s[256];
    int t = threadIdx.x;
    s[t] = (t < nb) ? bsum[t] : 0;
    __syncthreads();
    for (int off = 1; off < 256; off <<= 1) {
        int v = (t >= off) ? s[t - off] : 0;
        __syncthreads();
        s[t] += v;
        __syncthreads();
    }
    if (t < nb) boff[t] = (t == 0) ? 0 : s[t - 1];
    if (t == 255) *rowptrN = s[255];
}

// phase 3: local exclusive scan of each chunk + chunk offset -> rowptr, cursor
__global__ __launch_bounds__(256) void scan_part3(const int* __restrict__ degi,
                                                  const int* __restrict__ boff,
                                                  int* __restrict__ rowptr,
                                                  int* __restrict__ cursor, int N)
{
    int t  = threadIdx.x;
    int g2 = blockIdx.x * 256 + t;
    int n2 = N >> 1;
    int2 d = (g2 < n2) ? ((const int2*)degi)[g2] : make_int2(0, 0);
    __shared__ int s[256];
    s[t] = d.x + d.y;
    __syncthreads();
    for (int off = 1; off < 256; off <<= 1) {
        int v = (t >= off) ? s[t - off] : 0;
        __syncthreads();
        s[t] += v;
        __syncthreads();
    }
    int off0 = boff[blockIdx.x] + ((t == 0) ? 0 : s[t - 1]);
    if (g2 < n2) {
        int i = g2 * 2;
        rowptr[i]     = off0;
        rowptr[i + 1] = off0 + d.x;
        cursor[i]     = off0;
        cursor[i + 1] = off0 + d.x;
    }
}

// eidx[pos] = src, edges grouped by dst
__global__ __launch_bounds__(256) void scatter_kernel(const int* __restrict__ src,
                                                      const int* __restrict__ dst,
                                                      int* __restrict__ cursor,
                                                      int* __restrict__ eidx, int E)
{
    int e = blockIdx.x * 256 + threadIdx.x;
    if (e >= E) return;
    int pos = atomicAdd(&cursor[dst[e]], 1);
    eidx[pos] = src[e];
}

// ---- layer 1: fused pull-aggregation (6 ch) + matmul ----------------------
__global__ __launch_bounds__(256) void sage1_fused(
    const int* __restrict__ rowptr, const int* __restrict__ eidx,
    const float* __restrict__ x,
    const float* __restrict__ Wl, const float* __restrict__ bias,
    const float* __restrict__ Wr, float* __restrict__ out, int n)
{
    __shared__ float4 sWl[6 * 16];
    __shared__ float4 sWr[6 * 16];
    for (int i = threadIdx.x; i < 6 * 16; i += 256) {
        sWl[i] = ((const float4*)Wl)[i];
        sWr[i] = ((const float4*)Wr)[i];
    }
    __syncthreads();

    int node = blockIdx.x * 256 + threadIdx.x;
    if (node >= n) return;

    int b = rowptr[node], e = rowptr[node + 1];
    float a[6] = {0.f, 0.f, 0.f, 0.f, 0.f, 0.f};
    for (int j = b; j < e; j++) {
        int s = eidx[j];
        const float2* r = (const float2*)(x + (size_t)s * 6);
        float2 r0 = r[0], r1 = r[1], r2 = r[2];
        a[0] += r0.x; a[1] += r0.y; a[2] += r1.x;
        a[3] += r1.y; a[4] += r2.x; a[5] += r2.y;
    }
    float invd = 1.0f / fmaxf((float)(e - b), 1.0f);

    const float2* xr2 = (const float2*)(x + (size_t)node * 6);
    float2 x0 = xr2[0], x1 = xr2[1], x2 = xr2[2];
    float hh[6] = {x0.x, x0.y, x1.x, x1.y, x2.x, x2.y};

    float4 acc[16];
#pragma unroll
    for (int cg = 0; cg < 16; cg++) acc[cg] = ((const float4*)bias)[cg];
#pragma unroll
    for (int k = 0; k < 6; k++) {
        float am = a[k] * invd;
        float hk = hh[k];
#pragma unroll
        for (int cg = 0; cg < 16; cg++) {
            float4 wl = sWl[k * 16 + cg];
            float4 wr = sWr[k * 16 + cg];
            acc[cg].x = fmaf(am, wl.x, fmaf(hk, wr.x, acc[cg].x));
            acc[cg].y = fmaf(am, wl.y, fmaf(hk, wr.y, acc[cg].y));
            acc[cg].z = fmaf(am, wl.z, fmaf(hk, wr.z, acc[cg].z));
            acc[cg].w = fmaf(am, wl.w, fmaf(hk, wr.w, acc[cg].w));
        }
    }
    float4* orow = (float4*)(out + (size_t)node * 64);
#pragma unroll
    for (int cg = 0; cg < 16; cg++) orow[cg] = acc[cg];
}

// ---- 64-ch pull aggregation: one wave per node, lane = channel ------------
__global__ __launch_bounds__(256) void aggpull64(const int* __restrict__ rowptr,
                                                 const int* __restrict__ eidx,
                                                 const float* __restrict__ h,
                                                 float* __restrict__ agg, int n)
{
    int w    = (blockIdx.x * 256 + threadIdx.x) >> 6;
    int lane = threadIdx.x & 63;
    if (w >= n) return;
    int b = rowptr[w], e = rowptr[w + 1];
    float acc0 = 0.f, acc1 = 0.f, acc2 = 0.f, acc3 = 0.f;
    for (int j0 = b; j0 < e; j0 += 64) {
        int myidx = (j0 + lane < e) ? eidx[j0 + lane] : 0;
        int m = min(64, e - j0);
        int jj = 0;
        for (; jj + 4 <= m; jj += 4) {
            int s0 = __shfl(myidx, jj,     64);
            int s1 = __shfl(myidx, jj + 1, 64);
            int s2 = __shfl(myidx, jj + 2, 64);
            int s3 = __shfl(myidx, jj + 3, 64);
            acc0 += h[(size_t)s0 * 64 + lane];
            acc1 += h[(size_t)s1 * 64 + lane];
            acc2 += h[(size_t)s2 * 64 + lane];
            acc3 += h[(size_t)s3 * 64 + lane];
        }
        for (; jj < m; jj++) {
            int s = __shfl(myidx, jj, 64);
            acc0 += h[(size_t)s * 64 + lane];
        }
    }
    agg[(size_t)w * 64 + lane] = acc0 + acc1 + acc2 + acc3;
}

// out[i][:] = (agg[i]/max(deg,1)) @ Wl + bias + hin[i] @ Wr, 2 nodes/thread
__global__ __launch_bounds__(256) void sage_matmul64(
    const float* __restrict__ agg, const float* __restrict__ hin,
    const int* __restrict__ rowptr, const float* __restrict__ Wl,
    const float* __restrict__ bias, const float* __restrict__ Wr,
    float* __restrict__ out, int n)
{
    __shared__ float4 sWl[64 * 16];
    __shared__ float4 sWr[64 * 16];
    for (int i = threadIdx.x; i < 64 * 16; i += 256) {
        sWl[i] = ((const float4*)Wl)[i];
        sWr[i] = ((const float4*)Wr)[i];
    }
    __syncthreads();

    int node0 = blockIdx.x * 512 + threadIdx.x;
    if (node0 >= n) return;
    int  node1 = node0 + 256;
    bool has1  = (node1 < n);
    int  n1    = has1 ? node1 : node0;

    float invd0 = 1.0f / fmaxf((float)(rowptr[node0 + 1] - rowptr[node0]), 1.0f);
    float invd1 = 1.0f / fmaxf((float)(rowptr[n1 + 1] - rowptr[n1]), 1.0f);

    float4 acc0[16], acc1[16];
#pragma unroll
    for (int cg = 0; cg < 16; cg++) {
        float4 bv = ((const float4*)bias)[cg];
        acc0[cg] = bv;
        acc1[cg] = bv;
    }

    const float4* ar0 = (const float4*)(agg + (size_t)node0 * 64);
    const float4* hr0 = (const float4*)(hin + (size_t)node0 * 64);
    const float4* ar1 = (const float4*)(agg + (size_t)n1 * 64);
    const float4* hr1 = (const float4*)(hin + (size_t)n1 * 64);

#pragma unroll 1   // keep body ~10KB: fits L1I; inner j/cg fully unrolled
    for (int k4 = 0; k4 < 16; k4++) {
        float4 a0 = ar0[k4], h0 = hr0[k4];
        float4 a1 = ar1[k4], h1 = hr1[k4];
        float aa0[4] = {a0.x, a0.y, a0.z, a0.w}, hh0[4] = {h0.x, h0.y, h0.z, h0.w};
        float aa1[4] = {a1.x, a1.y, a1.z, a1.w}, hh1[4] = {h1.x, h1.y, h1.z, h1.w};
#pragma unroll
        for (int j = 0; j < 4; j++) {
            float am0 = aa0[j] * invd0, hk0 = hh0[j];
            float am1 = aa1[j] * invd1, hk1 = hh1[j];
            int k = k4 * 4 + j;
#pragma unroll
            for (int cg = 0; cg < 16; cg++) {
                float4 wl = sWl[k * 16 + cg];
                float4 wr = sWr[k * 16 + cg];
                acc0[cg].x = fmaf(am0, wl.x, fmaf(hk0, wr.x, acc0[cg].x));
                acc0[cg].y = fmaf(am0, wl.y, fmaf(hk0, wr.y, acc0[cg].y));
                acc0[cg].z = fmaf(am0, wl.z, fmaf(hk0, wr.z, acc0[cg].z));
                acc0[cg].w = fmaf(am0, wl.w, fmaf(hk0, wr.w, acc0[cg].w));
                acc1[cg].x = fmaf(am1, wl.x, fmaf(hk1, wr.x, acc1[cg].x));
                acc1[cg].y = fmaf(am1, wl.y, fmaf(hk1, wr.y, acc1[cg].y));
                acc1[cg].z = fmaf(am1, wl.z, fmaf(hk1, wr.z, acc1[cg].z));
                acc1[cg].w = fmaf(am1, wl.w, fmaf(hk1, wr.w, acc1[cg].w));
            }
        }
    }
    float4* o0 = (float4*)(out + (size_t)node0 * 64);
#pragma unroll
    for (int cg = 0; cg < 16; cg++) o0[cg] = acc0[cg];
    if (has1) {
        float4* o1 = (float4*)(out + (size_t)node1 * 64);
#pragma unroll
        for (int cg = 0; cg < 16; cg++) o1[cg] = acc1[cg];
    }
}

// ---- BatchNorm ------------------------------------------------------------

__global__ __launch_bounds__(256) void bn_stats(const float* __restrict__ h,
                                                float* __restrict__ stats, size_t total)
{
    __shared__ float ls[64], lss[64];
    if (threadIdx.x < 64) { ls[threadIdx.x] = 0.f; lss[threadIdx.x] = 0.f; }
    __syncthreads();
    float s = 0.f, ss = 0.f;
    size_t stride = (size_t)gridDim.x * 256;
    for (size_t i = (size_t)blockIdx.x * 256 + threadIdx.x; i < total; i += stride) {
        float v = h[i];
        s += v;
        ss = fmaf(v, v, ss);
    }
    int c = threadIdx.x & 63;
    atomicAdd(&ls[c], s);
    atomicAdd(&lss[c], ss);
    __syncthreads();
    if (threadIdx.x < 64) {
        unsafeAtomicAdd(&stats[threadIdx.x], ls[threadIdx.x]);
        unsafeAtomicAdd(&stats[64 + threadIdx.x], lss[threadIdx.x]);
    }
}

__global__ __launch_bounds__(256) void bn_relu(float* __restrict__ h,
                                               const float* __restrict__ stats,
                                               const float* __restrict__ g,
                                               const float* __restrict__ be,
                                               float inv_n, size_t total)
{
    size_t i = (size_t)blockIdx.x * 256 + threadIdx.x;
    if (i >= total) return;
    int   c   = threadIdx.x & 63;
    float mu  = stats[c] * inv_n;
    float var = stats[64 + c] * inv_n - mu * mu;
    float sc  = g[c] / sqrtf(var + 1e-5f);
    float sh  = fmaf(-mu, sc, be[c]);
    h[i] = fmaxf(fmaf(h[i], sc, sh), 0.f);
}

// ---- pooling + heads ------------------------------------------------------

__global__ __launch_bounds__(256) void softmax_sum(const float* __restrict__ x,
                                                   float* __restrict__ sumexp, int n)
{
    float s = 0.f;
    int stride = gridDim.x * 256;
    for (int i = blockIdx.x * 256 + threadIdx.x; i < n; i += stride)
        s += expf(x[(size_t)i * 6 + 4]);
#pragma unroll
    for (int o = 32; o > 0; o >>= 1) s += __shfl_down(s, o, 64);
    __shared__ float wsum[4];
    if ((threadIdx.x & 63) == 0) wsum[threadIdx.x >> 6] = s;
    __syncthreads();
    if (threadIdx.x == 0)
        unsafeAtomicAdd(sumexp, wsum[0] + wsum[1] + wsum[2] + wsum[3]);
}

__global__ void seg_bounds(const int* __restrict__ batch, int* __restrict__ lb, int n)
{
    int b = threadIdx.x;
    if (b > 64) return;
    int lo = 0, hi = n;
    while (lo < hi) {
        int mid = (lo + hi) >> 1;
        if (batch[mid] < b) lo = mid + 1; else hi = mid;
    }
    lb[b] = lo;
}

__global__ __launch_bounds__(256) void pool_kernel(const float* __restrict__ h,
                                                   const float* __restrict__ x,
                                                   const int* __restrict__ lb,
                                                   const float* __restrict__ sumexp,
                                                   float* __restrict__ pool, int n)
{
    int b = blockIdx.x;
    int start = lb[b], end = lb[b + 1];
    int c = threadIdx.x & 63, grp = threadIdx.x >> 6;
    float inv_se = 1.0f / sumexp[0];
    float acc = 0.f;
    for (int i = start + grp; i < end; i += 4) {
        float w = expf(x[(size_t)i * 6 + 4]) * inv_se;
        acc = fmaf(h[(size_t)i * 64 + c], w, acc);
    }
    __shared__ float red[4][64];
    red[grp][c] = acc;
    __syncthreads();
    if (grp == 0) {
        float cnt = (float)(end - start);
        pool[b * 64 + c] = (red[0][c] + red[1][c] + red[2][c] + red[3][c]) / fmaxf(cnt, 1.0f);
    }
}

__global__ __launch_bounds__(64) void heads_kernel(
    const float* __restrict__ pool,
    const float* __restrict__ phW1, const float* __restrict__ phb1,
    const float* __restrict__ phW2, const float* __restrict__ phb2,
    const float* __restrict__ trW1, const float* __restrict__ trb1,
    const float* __restrict__ trW2, const float* __restrict__ trb2,
    float* __restrict__ out)
{
    int b = blockIdx.x, t = threadIdx.x;
    __shared__ float p[64], h1[32], h2[16];
    p[t] = pool[b * 64 + t];
    __syncthreads();
    if (t < 32) {
        float s = phb1[t];
        for (int k = 0; k < 64; k++) s = fmaf(p[k], phW1[k * 32 + t], s);
        h1[t] = fmaxf(s, 0.f);
    } else if (t < 48) {
        int tt = t - 32;
        float s = trb1[tt];
        for (int k = 0; k < 64; k++) s = fmaf(p[k], trW1[k * 16 + tt], s);
        h2[tt] = fmaxf(s, 0.f);
    }
    __syncthreads();
    if (t < 3) {
        float s = phb2[t];
        for (int k = 0; k < 32; k++) s = fmaf(h1[k], phW2[k * 3 + t], s);
        out[b * 3 + t] = s;
    } else if (t == 63) {
        float s = trb2[0];
        for (int k = 0; k < 16; k++) s = fmaf(h2[k], trW2[k], s);
        out[192 + b] = 1.0f / (1.0f + expf(-s));
    }
}

extern "C" void kernel_launch(void* const* d_in, const int* in_sizes, int n_in,
                              void* d_out, int out_size, void* d_ws, size_t ws_size,
                              hipStream_t stream)
{
    const float* x     = (const float*)d_in[0];
    const int*   ei    = (const int*)d_in[1];
    const int*   batch = (const int*)d_in[2];
    const float* W1l = (const float*)d_in[3];
    const float* b1  = (const float*)d_in[4];
    const float* W1r = (const float*)d_in[5];
    const float* W2l = (const float*)d_in[6];
    const float* b2  = (const float*)d_in[7];
    const float* W2r = (const float*)d_in[8];
    const float* W3l = (const float*)d_in[9];
    const float* b3  = (const float*)d_in[10];
    const float* W3r = (const float*)d_in[11];
    const float* g1  = (const float*)d_in[12];
    const float* be1 = (const float*)d_in[13];
    const float* g2  = (const float*)d_in[14];
    const float* be2 = (const float*)d_in[15];
    const float* g3  = (const float*)d_in[16];
    const float* be3 = (const float*)d_in[17];
    const float* phW1 = (const float*)d_in[18];
    const float* phb1 = (const float*)d_in[19];
    const float* phW2 = (const float*)d_in[20];
    const float* phb2 = (const float*)d_in[21];
    const float* trW1 = (const float*)d_in[22];
    const float* trb1 = (const float*)d_in[23];
    const float* trW2 = (const float*)d_in[24];
    const float* trb2 = (const float*)d_in[25];

    const int N = in_sizes[0] / 6;   // even
    const int E = in_sizes[1] / 2;
    const int* src = ei;
    const int* dst = ei + E;

    float* ws = (float*)d_ws;
    const size_t N64 = (size_t)N * 64;
    float* agg    = ws;                       // N*64
    float* hA     = ws + N64;                 // N*64
    float* hB     = ws + 2 * N64;             // N*64
    // --- contiguous zero-init region: degi + stats[3][128] + sumexp ---
    int*   degi   = (int*)(ws + 3 * N64);     // N
    float* stats  = (float*)(degi + N);       // 3 * 128
    float* sumexp = stats + 384;              // 1 (pad 4)
    // --- end zero region ---
    int*   rowptr = (int*)(sumexp + 4);       // N+1
    int*   cursor = rowptr + N + 1;           // N
    int*   eidx   = cursor + N;               // E
    int*   bsum   = eidx + E;                 // 256
    int*   boff   = bsum + 256;               // 256
    int*   lb     = boff + 256;               // 65 (pad 72)
    float* pool   = (float*)(lb + 72);        // 64*64
    float* out    = (float*)d_out;

    const int nodeBlocks = (N + 255) / 256;
    const int edgeBlocks = (E + 255) / 256;
    const int waveNodeBlocks = (int)(((size_t)N * 64 + 255) / 256);
    const int ewBlocks = (int)((N64 + 255) / 256);
    const int scanBlocks = ((N >> 1) + 255) / 256;    // 196 for N=100000
    const int mm2Blocks = (N + 511) / 512;
    const float invN = 1.0f / (float)N;

    // ---- CSR build (edges grouped by dst; eidx stores src) ----
    size_t zbytes = (char*)(sumexp + 4) - (char*)degi;
    hipMemsetAsync(degi, 0, zbytes, stream);
    hist_kernel<<<edgeBlocks, 256, 0, stream>>>(dst, degi, E);
    scan_part1<<<scanBlocks, 256, 0, stream>>>(degi, bsum, N);
    scan_part2<<<1, 256, 0, stream>>>(bsum, boff, rowptr + N, scanBlocks);
    scan_part3<<<scanBlocks, 256, 0, stream>>>(degi, boff, rowptr, cursor, N);
    scatter_kernel<<<edgeBlocks, 256, 0, stream>>>(src, dst, cursor, eidx, E);

    // ---- layer 1 (6 ch, aggregation fused into matmul) ----
    sage1_fused<<<nodeBlocks, 256, 0, stream>>>(rowptr, eidx, x, W1l, b1, W1r, hA, N);
    bn_stats<<<1024, 256, 0, stream>>>(hA, stats, N64);
    bn_relu<<<ewBlocks, 256, 0, stream>>>(hA, stats, g1, be1, invN, N64);

    // ---- layer 2 ----
    aggpull64<<<waveNodeBlocks, 256, 0, stream>>>(rowptr, eidx, hA, agg, N);
    sage_matmul64<<<mm2Blocks, 256, 0, stream>>>(agg, hA, rowptr, W2l, b2, W2r, hB, N);
    bn_stats<<<1024, 256, 0, stream>>>(hB, stats + 128, N64);
    bn_relu<<<ewBlocks, 256, 0, stream>>>(hB, stats + 128, g2, be2, invN, N64);

    // ---- layer 3 ----
    aggpull64<<<waveNodeBlocks, 256, 0, stream>>>(rowptr, eidx, hB, agg, N);
    sage_matmul64<<<mm2Blocks, 256, 0, stream>>>(agg, hB, rowptr, W3l, b3, W3r, hA, N);
    bn_stats<<<1024, 256, 0, stream>>>(hA, stats + 256, N64);
    bn_relu<<<ewBlocks, 256, 0, stream>>>(hA, stats + 256, g3, be3, invN, N64);

    // ---- attention pooling + heads ----
    softmax_sum<<<256, 256, 0, stream>>>(x, sumexp, N);
    seg_bounds<<<1, 128, 0, stream>>>(batch, lb, N);
    pool_kernel<<<64, 256, 0, stream>>>(hA, x, lb, sumexp, pool, N);
    heads_kernel<<<64, 64, 0, stream>>>(pool, phW1, phb1, phW2, phb2,
                                        trW1, trb1, trW2, trb2, out);
}